// Round 1
// baseline (500.665 us; speedup 1.0000x reference)
//
#include <hip/hip_runtime.h>

// ImageLRU: per-position (b,c,h,w) log-scan over n=64 vectors of length L=16.
// out[i] = Lam ∘ out[i-step] + B @ out[i]  (complex), 6 stages, then
// y = Re(C @ out) + D @ img.
// One block = one position; state lives in LDS; matrix rows in registers.

namespace {

constexpr int Lc = 16;
constexpr int Nn = 64;

__global__ __launch_bounds__(256) void lru_scan_kernel(
    const float* __restrict__ x,
    const float* __restrict__ Lre, const float* __restrict__ Lim,
    const float* __restrict__ Bre, const float* __restrict__ Bim,
    const float* __restrict__ Cre, const float* __restrict__ Cim,
    const float* __restrict__ Dm,
    float* __restrict__ y)
{
    // complex state, row padded to 18 float2 (144 B = 16B-aligned, bank-shift 4/row)
    __shared__ float2 st[Nn][18];
    // real copy of input for the D term, row padded to 20 floats (80 B)
    __shared__ float img[Nn][20];

    const int tid = threadIdx.x;
    const size_t base = (size_t)blockIdx.x * (Nn * Lc);

    // ---- load x (1024 floats, coalesced float4) -> st (imag=0) and img ----
    {
        const float4 v = *reinterpret_cast<const float4*>(x + base + tid * 4);
        const int i = tid >> 2;          // vector index
        const int l = (tid & 3) * 4;     // element within vector
        float4* srow = reinterpret_cast<float4*>(&st[i][l]);
        srow[0] = make_float4(v.x, 0.f, v.y, 0.f);
        srow[1] = make_float4(v.z, 0.f, v.w, 0.f);
        *reinterpret_cast<float4*>(&img[i][l]) = v;
    }

    const int k = tid & 15;   // output element this thread owns
    const int g = tid >> 4;   // vector group (16 groups, stride-16 vectors)

    // ---- matrix rows k into registers ----
    float br[Lc], bi[Lc], cr[Lc], ci[Lc], dd[Lc];
    #pragma unroll
    for (int q = 0; q < 4; ++q) {
        const float4 t0 = reinterpret_cast<const float4*>(Bre + k * Lc)[q];
        const float4 t1 = reinterpret_cast<const float4*>(Bim + k * Lc)[q];
        const float4 t2 = reinterpret_cast<const float4*>(Cre + k * Lc)[q];
        const float4 t3 = reinterpret_cast<const float4*>(Cim + k * Lc)[q];
        const float4 t4 = reinterpret_cast<const float4*>(Dm  + k * Lc)[q];
        br[4*q+0]=t0.x; br[4*q+1]=t0.y; br[4*q+2]=t0.z; br[4*q+3]=t0.w;
        bi[4*q+0]=t1.x; bi[4*q+1]=t1.y; bi[4*q+2]=t1.z; bi[4*q+3]=t1.w;
        cr[4*q+0]=t2.x; cr[4*q+1]=t2.y; cr[4*q+2]=t2.z; cr[4*q+3]=t2.w;
        ci[4*q+0]=t3.x; ci[4*q+1]=t3.y; ci[4*q+2]=t3.z; ci[4*q+3]=t3.w;
        dd[4*q+0]=t4.x; dd[4*q+1]=t4.y; dd[4*q+2]=t4.z; dd[4*q+3]=t4.w;
    }
    const float lamr = Lre[k];
    const float lami = Lim[k];

    __syncthreads();

    // ---- 6 scan stages: new[i] = Lam*st[i-step] + B @ st[i]  (i >= step) ----
    #pragma unroll
    for (int d = 0; d < 6; ++d) {
        const int step = 1 << d;
        float accr[4], acci[4];
        #pragma unroll
        for (int p = 0; p < 4; ++p) {
            const int i = p * 16 + g;
            if (i >= step) {
                const float2 left = st[i - step][k];
                float ar = lamr * left.x - lami * left.y;
                float ai = lamr * left.y + lami * left.x;
                const float4* row = reinterpret_cast<const float4*>(&st[i][0]);
                #pragma unroll
                for (int l2 = 0; l2 < 8; ++l2) {
                    const float4 q2 = row[l2];   // complex elems 2*l2, 2*l2+1
                    const int l = 2 * l2;
                    ar = fmaf(br[l],    q2.x, ar);
                    ar = fmaf(-bi[l],   q2.y, ar);
                    ai = fmaf(br[l],    q2.y, ai);
                    ai = fmaf(bi[l],    q2.x, ai);
                    ar = fmaf(br[l+1],  q2.z, ar);
                    ar = fmaf(-bi[l+1], q2.w, ar);
                    ai = fmaf(br[l+1],  q2.w, ai);
                    ai = fmaf(bi[l+1],  q2.z, ai);
                }
                accr[p] = ar; acci[p] = ai;
            }
        }
        __syncthreads();   // all reads of old state complete
        #pragma unroll
        for (int p = 0; p < 4; ++p) {
            const int i = p * 16 + g;
            if (i >= step) st[i][k] = make_float2(accr[p], acci[p]);
        }
        __syncthreads();   // writes visible before next stage
    }

    // ---- epilogue: y = Re(C @ st) + D @ img ; coalesced dword stores ----
    #pragma unroll
    for (int p = 0; p < 4; ++p) {
        const int i = p * 16 + g;
        const float4* srow = reinterpret_cast<const float4*>(&st[i][0]);
        const float4* irow = reinterpret_cast<const float4*>(&img[i][0]);
        float r = 0.f;
        #pragma unroll
        for (int l2 = 0; l2 < 8; ++l2) {
            const float4 q2 = srow[l2];
            const int l = 2 * l2;
            r = fmaf(cr[l],    q2.x, r);
            r = fmaf(-ci[l],   q2.y, r);
            r = fmaf(cr[l+1],  q2.z, r);
            r = fmaf(-ci[l+1], q2.w, r);
        }
        #pragma unroll
        for (int l4 = 0; l4 < 4; ++l4) {
            const float4 m = irow[l4];
            const int l = 4 * l4;
            r = fmaf(dd[l],   m.x, r);
            r = fmaf(dd[l+1], m.y, r);
            r = fmaf(dd[l+2], m.z, r);
            r = fmaf(dd[l+3], m.w, r);
        }
        y[base + p * 256 + tid] = r;  // (p*16+g)*16 + k == p*256 + tid
    }
}

} // namespace

extern "C" void kernel_launch(void* const* d_in, const int* in_sizes, int n_in,
                              void* d_out, int out_size, void* d_ws, size_t ws_size,
                              hipStream_t stream) {
    const float* x   = (const float*)d_in[0];
    const float* Lre = (const float*)d_in[1];
    const float* Lim = (const float*)d_in[2];
    const float* Bre = (const float*)d_in[3];
    const float* Bim = (const float*)d_in[4];
    const float* Cre = (const float*)d_in[5];
    const float* Cim = (const float*)d_in[6];
    const float* Dm  = (const float*)d_in[7];
    float* y = (float*)d_out;

    const int positions = in_sizes[0] / (Nn * Lc);  // 32768
    lru_scan_kernel<<<positions, 256, 0, stream>>>(x, Lre, Lim, Bre, Bim, Cre, Cim, Dm, y);
}

// Round 2
// 243.757 us; speedup vs baseline: 2.0540x; 2.0540x over previous
//
#include <hip/hip_runtime.h>

// ImageLRU as one GEMM: y[r,:] = W @ x[r,:], W = Re(C·T) + I⊗D built on device.
// T_{i,j} = ordered product over stages d=5..0 of F_{2^d}:
//   F_s = Λ (diag)  if bit_s(i-j) set
//       = B         else if (j + ((i-j) mod s)) >= s
//       = I         otherwise
// W is block-lower-triangular: K-loop per N-tile stops at (nb+1)*128.
// fp32 accuracy via 3-term bf16 split: Xh*Wh + Xl*Wh + Xh*Wl.

namespace {

typedef __attribute__((ext_vector_type(8))) short short8v;
typedef __attribute__((ext_vector_type(4))) float f32x4;

__device__ inline unsigned short f2bf_rne(float f) {
    unsigned u = __builtin_bit_cast(unsigned, f);
    u += 0x7fffu + ((u >> 16) & 1u);
    return (unsigned short)(u >> 16);
}
__device__ inline float bf2f(unsigned short h) {
    unsigned u = ((unsigned)h) << 16;
    return __builtin_bit_cast(float, u);
}

// ---------------- prep: build Wh/Wl (bf16 hi/lo of W) ----------------
__global__ __launch_bounds__(256) void build_w_kernel(
    const float* __restrict__ Lre, const float* __restrict__ Lim,
    const float* __restrict__ Bre, const float* __restrict__ Bim,
    const float* __restrict__ Cre, const float* __restrict__ Cim,
    const float* __restrict__ Dm,
    unsigned short* __restrict__ Wh, unsigned short* __restrict__ Wl)
{
    const int i = blockIdx.x >> 6, j = blockIdx.x & 63;
    const int t = threadIdx.x, k = t >> 4, l = t & 15;
    const int widx = (i * 16 + k) * 1024 + j * 16 + l;

    if (j > i) { Wh[widx] = 0; Wl[widx] = 0; return; }

    __shared__ float2 Bs[16][16];
    __shared__ float2 M[16][16];
    Bs[k][l] = make_float2(Bre[t], Bim[t]);
    M[k][l]  = make_float2(k == l ? 1.f : 0.f, 0.f);
    const int delta = i - j;
    __syncthreads();

    #pragma unroll
    for (int d = 0; d < 6; ++d) {
        const int s = 1 << d;
        if (delta & s) {
            // M <- Lam * M  (row scale, no cross-thread dep)
            const float lr = Lre[k], li = Lim[k];
            const float2 m0 = M[k][l];
            M[k][l] = make_float2(lr * m0.x - li * m0.y, lr * m0.y + li * m0.x);
            __syncthreads();
        } else if (j + (delta & (s - 1)) >= s) {
            // M <- B @ M
            float2 acc = make_float2(0.f, 0.f);
            #pragma unroll
            for (int m = 0; m < 16; ++m) {
                const float2 b = Bs[k][m], v = M[m][l];
                acc.x += b.x * v.x - b.y * v.y;
                acc.y += b.x * v.y + b.y * v.x;
            }
            __syncthreads();
            M[k][l] = acc;
            __syncthreads();
        }
    }

    // w = Re(C @ M)[k][l] (+ D on the block diagonal)
    float w = 0.f;
    #pragma unroll
    for (int m = 0; m < 16; ++m) {
        const float2 v = M[m][l];
        w += Cre[k * 16 + m] * v.x - Cim[k * 16 + m] * v.y;
    }
    if (i == j) w += Dm[t];
    const unsigned short h = f2bf_rne(w);
    Wh[widx] = h;
    Wl[widx] = f2bf_rne(w - bf2f(h));
}

// ---------------- main GEMM: Y[32768,1024] = X @ W^T ----------------
// BM=128, BN=128, BK=32 (fp32 K). 256 thr = 4 waves (2x2), 64x64/wave.
// LDS tiles [128 rows][32 k] bf16, 16B-group XOR-swizzled by (row>>1)&3.

__device__ inline int lds_off(int row, int grp) {           // byte offset
    return row * 64 + (((grp ^ ((row >> 1) & 3)) << 4));
}

__global__ __launch_bounds__(256) void gemm_kernel(
    const float* __restrict__ X,
    const unsigned short* __restrict__ Wh,
    const unsigned short* __restrict__ Wl,
    float* __restrict__ Y)
{
    __shared__ alignas(16) unsigned short s_xh[128 * 32];
    __shared__ alignas(16) unsigned short s_xl[128 * 32];
    __shared__ alignas(16) unsigned short s_wh[128 * 32];
    __shared__ alignas(16) unsigned short s_wl[128 * 32];

    const int bid = blockIdx.x;
    const int nb = bid & 7;      // N-tile (8 total)
    const int mt = bid >> 3;     // M-tile (256 total)
    const int t = threadIdx.x;
    const int wid = t >> 6;
    const int lane = t & 63;
    const int wr = wid >> 1, wc = wid & 1;
    const int l15 = lane & 15, lg = lane >> 4;
    const int nk = (nb + 1) * 4; // K-chunks of 32 (triangular limit)

    f32x4 acc[4][4] = {};

    for (int kc = 0; kc < nk; ++kc) {
        __syncthreads();
        // ---- stage X tile: 128x32 fp32 -> hi/lo bf16 ----
        #pragma unroll
        for (int p = 0; p < 4; ++p) {
            const int f = p * 256 + t;          // float4 id in [0,1024)
            const int row = f >> 3, fc = f & 7; // fc: float4-col
            const float4 v = *reinterpret_cast<const float4*>(
                X + (size_t)(mt * 128 + row) * 1024 + kc * 32 + fc * 4);
            const unsigned short h0 = f2bf_rne(v.x), h1 = f2bf_rne(v.y),
                                 h2 = f2bf_rne(v.z), h3 = f2bf_rne(v.w);
            ushort4 hv; hv.x = h0; hv.y = h1; hv.z = h2; hv.w = h3;
            ushort4 lv;
            lv.x = f2bf_rne(v.x - bf2f(h0));
            lv.y = f2bf_rne(v.y - bf2f(h1));
            lv.z = f2bf_rne(v.z - bf2f(h2));
            lv.w = f2bf_rne(v.w - bf2f(h3));
            const int off = lds_off(row, fc >> 1) + ((fc & 1) << 3);
            *reinterpret_cast<ushort4*>(reinterpret_cast<char*>(s_xh) + off) = hv;
            *reinterpret_cast<ushort4*>(reinterpret_cast<char*>(s_xl) + off) = lv;
        }
        // ---- stage W tiles: [128 n][32 k] bf16 ----
        #pragma unroll
        for (int p = 0; p < 2; ++p) {
            const int id = p * 256 + t;          // 16B-group id in [0,512)
            const int row = id >> 2, g = id & 3;
            const size_t gof = (size_t)(nb * 128 + row) * 1024 + kc * 32 + g * 8;
            const int off = lds_off(row, g);
            *reinterpret_cast<short8v*>(reinterpret_cast<char*>(s_wh) + off) =
                *reinterpret_cast<const short8v*>(Wh + gof);
            *reinterpret_cast<short8v*>(reinterpret_cast<char*>(s_wl) + off) =
                *reinterpret_cast<const short8v*>(Wl + gof);
        }
        __syncthreads();

        // ---- fragments + MFMA ----
        short8v ah[4], al[4], bh[4], bl[4];
        #pragma unroll
        for (int mm = 0; mm < 4; ++mm) {
            const int row = wr * 64 + mm * 16 + l15;
            const int off = lds_off(row, lg);
            ah[mm] = *reinterpret_cast<const short8v*>(reinterpret_cast<char*>(s_xh) + off);
            al[mm] = *reinterpret_cast<const short8v*>(reinterpret_cast<char*>(s_xl) + off);
        }
        #pragma unroll
        for (int nn = 0; nn < 4; ++nn) {
            const int row = wc * 64 + nn * 16 + l15;
            const int off = lds_off(row, lg);
            bh[nn] = *reinterpret_cast<const short8v*>(reinterpret_cast<char*>(s_wh) + off);
            bl[nn] = *reinterpret_cast<const short8v*>(reinterpret_cast<char*>(s_wl) + off);
        }
        #pragma unroll
        for (int mm = 0; mm < 4; ++mm) {
            #pragma unroll
            for (int nn = 0; nn < 4; ++nn) {
                acc[mm][nn] = __builtin_amdgcn_mfma_f32_16x16x32_bf16(
                    ah[mm], bh[nn], acc[mm][nn], 0, 0, 0);
                acc[mm][nn] = __builtin_amdgcn_mfma_f32_16x16x32_bf16(
                    al[mm], bh[nn], acc[mm][nn], 0, 0, 0);
                acc[mm][nn] = __builtin_amdgcn_mfma_f32_16x16x32_bf16(
                    ah[mm], bl[nn], acc[mm][nn], 0, 0, 0);
            }
        }
    }

    // ---- epilogue: C/D layout col=lane&15, row=(lane>>4)*4+q ----
    #pragma unroll
    for (int mm = 0; mm < 4; ++mm) {
        const int grow = mt * 128 + wr * 64 + mm * 16 + lg * 4;
        #pragma unroll
        for (int nn = 0; nn < 4; ++nn) {
            const int gcol = nb * 128 + wc * 64 + nn * 16 + l15;
            #pragma unroll
            for (int q = 0; q < 4; ++q)
                Y[(size_t)(grow + q) * 1024 + gcol] = acc[mm][nn][q];
        }
    }
}

} // namespace

extern "C" void kernel_launch(void* const* d_in, const int* in_sizes, int n_in,
                              void* d_out, int out_size, void* d_ws, size_t ws_size,
                              hipStream_t stream) {
    const float* x   = (const float*)d_in[0];
    const float* Lre = (const float*)d_in[1];
    const float* Lim = (const float*)d_in[2];
    const float* Bre = (const float*)d_in[3];
    const float* Bim = (const float*)d_in[4];
    const float* Cre = (const float*)d_in[5];
    const float* Cim = (const float*)d_in[6];
    const float* Dm  = (const float*)d_in[7];
    float* y = (float*)d_out;

    unsigned short* Wh = (unsigned short*)d_ws;            // 1024*1024 bf16 = 2 MB
    unsigned short* Wl = Wh + 1024 * 1024;                 // 2 MB

    build_w_kernel<<<64 * 64, 256, 0, stream>>>(Lre, Lim, Bre, Bim, Cre, Cim, Dm, Wh, Wl);

    const int positions = in_sizes[0] / 1024;              // 32768
    gemm_kernel<<<(positions / 128) * 8, 256, 0, stream>>>(x, Wh, Wl, y);
}

// Round 3
// 179.411 us; speedup vs baseline: 2.7906x; 1.3586x over previous
//
#include <hip/hip_runtime.h>

// ImageLRU as one GEMM: y[r,:] = W @ x[r,:].
// R3: pre-split X into bf16 hi/lo ONCE (tiled, kgroup-major layout = LDS image),
// GEMM uses global_load_lds(16B) + conflict-free ds_read_b128 + 48 MFMA/barrier.
// Triangular W => per-N-tile K-limit; heavy tiles dispatched first (LPT).

namespace {

typedef __attribute__((ext_vector_type(8))) short short8v;
typedef __attribute__((ext_vector_type(4))) float f32x4;

__device__ inline unsigned short f2bf_rne(float f) {
    unsigned u = __builtin_bit_cast(unsigned, f);
    u += 0x7fffu + ((u >> 16) & 1u);
    return (unsigned short)(u >> 16);
}
__device__ inline float bf2f(unsigned short h) {
    unsigned u = ((unsigned)h) << 16;
    return __builtin_bit_cast(float, u);
}

__device__ inline void gld_lds16(const unsigned short* g, unsigned short* l) {
    __builtin_amdgcn_global_load_lds(
        (const __attribute__((address_space(1))) unsigned int*)g,
        (__attribute__((address_space(3))) unsigned int*)l, 16, 0, 0);
}

// Tiled layout for a [128 rows][32 k] bf16 tile: elem (row,k) at
//   tile_base + ((k>>3)<<10) + (row<<3) + (k&7)      (ushort units, 4096/tile)

// ---------------- prep: build Wh/Wl in tiled layout ----------------
__global__ __launch_bounds__(256) void build_w_kernel(
    const float* __restrict__ Lre, const float* __restrict__ Lim,
    const float* __restrict__ Bre, const float* __restrict__ Bim,
    const float* __restrict__ Cre, const float* __restrict__ Cim,
    const float* __restrict__ Dm,
    unsigned short* __restrict__ Wh, unsigned short* __restrict__ Wl)
{
    const int i = blockIdx.x >> 6, j = blockIdx.x & 63;
    const int t = threadIdx.x, k = t >> 4, l = t & 15;

    const int n_g = i * 16 + k;        // W row (n dim)
    const int k_g = j * 16 + l;        // W col (k dim)
    const size_t widx = (((size_t)((n_g >> 7) * 32 + (k_g >> 5))) << 12)
                      + (((k_g >> 3) & 3) << 10) + ((n_g & 127) << 3) + (k_g & 7);

    if (j > i) { Wh[widx] = 0; Wl[widx] = 0; return; }

    __shared__ float2 Bs[16][16];
    __shared__ float2 M[16][16];
    Bs[k][l] = make_float2(Bre[t], Bim[t]);
    M[k][l]  = make_float2(k == l ? 1.f : 0.f, 0.f);
    const int delta = i - j;
    __syncthreads();

    #pragma unroll
    for (int d = 0; d < 6; ++d) {
        const int s = 1 << d;
        if (delta & s) {
            const float lr = Lre[k], li = Lim[k];
            const float2 m0 = M[k][l];
            M[k][l] = make_float2(lr * m0.x - li * m0.y, lr * m0.y + li * m0.x);
            __syncthreads();
        } else if (j + (delta & (s - 1)) >= s) {
            float2 acc = make_float2(0.f, 0.f);
            #pragma unroll
            for (int m = 0; m < 16; ++m) {
                const float2 b = Bs[k][m], v = M[m][l];
                acc.x += b.x * v.x - b.y * v.y;
                acc.y += b.x * v.y + b.y * v.x;
            }
            __syncthreads();
            M[k][l] = acc;
            __syncthreads();
        }
    }

    float w = 0.f;
    #pragma unroll
    for (int m = 0; m < 16; ++m) {
        const float2 v = M[m][l];
        w += Cre[k * 16 + m] * v.x - Cim[k * 16 + m] * v.y;
    }
    if (i == j) w += Dm[t];
    const unsigned short h = f2bf_rne(w);
    Wh[widx] = h;
    Wl[widx] = f2bf_rne(w - bf2f(h));
}

// ---------------- prep: split X -> Xh/Xl (tiled layout) ----------------
__global__ __launch_bounds__(256) void split_x_kernel(
    const float* __restrict__ X,
    unsigned short* __restrict__ Xh, unsigned short* __restrict__ Xl)
{
    const int mt = blockIdx.x >> 5;    // 128-row tile
    const int kc = blockIdx.x & 31;    // 32-col chunk
    const int t = threadIdx.x;
    const size_t tb = ((size_t)(mt * 32 + kc)) << 12;

    #pragma unroll
    for (int p = 0; p < 4; ++p) {
        const int f = p * 256 + t;          // float4 id in [0,1024)
        const int row = f >> 3, c4 = f & 7;
        const float4 v = *reinterpret_cast<const float4*>(
            X + (size_t)(mt * 128 + row) * 1024 + kc * 32 + c4 * 4);
        ushort4 hv, lv;
        hv.x = f2bf_rne(v.x); lv.x = f2bf_rne(v.x - bf2f(hv.x));
        hv.y = f2bf_rne(v.y); lv.y = f2bf_rne(v.y - bf2f(hv.y));
        hv.z = f2bf_rne(v.z); lv.z = f2bf_rne(v.z - bf2f(hv.z));
        hv.w = f2bf_rne(v.w); lv.w = f2bf_rne(v.w - bf2f(hv.w));
        const size_t o = tb + ((size_t)(c4 >> 1) << 10) + (row << 3) + ((c4 & 1) << 2);
        *reinterpret_cast<ushort4*>(Xh + o) = hv;
        *reinterpret_cast<ushort4*>(Xl + o) = lv;
    }
}

// ---------------- main GEMM (path A): all-bf16, global_load_lds ----------------
__global__ __launch_bounds__(256) void gemm_tiled_kernel(
    const unsigned short* __restrict__ Xh, const unsigned short* __restrict__ Xl,
    const unsigned short* __restrict__ Wh, const unsigned short* __restrict__ Wl,
    float* __restrict__ Y, int mtiles)
{
    __shared__ alignas(16) unsigned short s_xh[4096];
    __shared__ alignas(16) unsigned short s_xl[4096];
    __shared__ alignas(16) unsigned short s_wh[4096];
    __shared__ alignas(16) unsigned short s_wl[4096];

    const int bid = blockIdx.x;
    const int nb = 7 - bid / mtiles;   // heavy N-tiles first (LPT)
    const int mt = bid % mtiles;
    const int t = threadIdx.x;
    const int wid = t >> 6, lane = t & 63;
    const int wr = wid >> 1, wc = wid & 1;
    const int l15 = lane & 15, lg = lane >> 4;
    const int nk = (nb + 1) * 4;

    f32x4 acc[4][4] = {};

    for (int kc = 0; kc < nk; ++kc) {
        __syncthreads();               // prior iter's ds_reads done
        const size_t xb = ((size_t)(mt * 32 + kc)) << 12;
        const size_t wb = ((size_t)(nb * 32 + kc)) << 12;
        #pragma unroll
        for (int p = 0; p < 2; ++p) {
            const int e8 = (p * 256 + t) * 8;   // ushort offset of this 16B slot
            gld_lds16(Xh + xb + e8, s_xh + e8);
            gld_lds16(Xl + xb + e8, s_xl + e8);
            gld_lds16(Wh + wb + e8, s_wh + e8);
            gld_lds16(Wl + wb + e8, s_wl + e8);
        }
        __syncthreads();               // drains vmcnt (compiler-inserted)

        short8v ah[4], al[4], bh[4], bl[4];
        #pragma unroll
        for (int mm = 0; mm < 4; ++mm) {
            const int o = (lg << 10) + ((wr * 64 + mm * 16 + l15) << 3);
            ah[mm] = *reinterpret_cast<const short8v*>(s_xh + o);
            al[mm] = *reinterpret_cast<const short8v*>(s_xl + o);
        }
        #pragma unroll
        for (int nn = 0; nn < 4; ++nn) {
            const int o = (lg << 10) + ((wc * 64 + nn * 16 + l15) << 3);
            bh[nn] = *reinterpret_cast<const short8v*>(s_wh + o);
            bl[nn] = *reinterpret_cast<const short8v*>(s_wl + o);
        }
        #pragma unroll
        for (int mm = 0; mm < 4; ++mm) {
            #pragma unroll
            for (int nn = 0; nn < 4; ++nn) {
                acc[mm][nn] = __builtin_amdgcn_mfma_f32_16x16x32_bf16(
                    ah[mm], bh[nn], acc[mm][nn], 0, 0, 0);
                acc[mm][nn] = __builtin_amdgcn_mfma_f32_16x16x32_bf16(
                    al[mm], bh[nn], acc[mm][nn], 0, 0, 0);
                acc[mm][nn] = __builtin_amdgcn_mfma_f32_16x16x32_bf16(
                    ah[mm], bl[nn], acc[mm][nn], 0, 0, 0);
            }
        }
    }

    #pragma unroll
    for (int mm = 0; mm < 4; ++mm) {
        const int grow = mt * 128 + wr * 64 + mm * 16 + lg * 4;
        #pragma unroll
        for (int nn = 0; nn < 4; ++nn) {
            const int gcol = nb * 128 + wc * 64 + nn * 16 + l15;
            #pragma unroll
            for (int q = 0; q < 4; ++q)
                Y[(size_t)(grow + q) * 1024 + gcol] = acc[mm][nn][q];
        }
    }
}

// ---------------- fallback (path B): R2 fused kernel, tiled W ----------------
__device__ inline int lds_off(int row, int grp) {
    return row * 64 + (((grp ^ ((row >> 1) & 3)) << 4));
}

__global__ __launch_bounds__(256) void gemm_fused_kernel(
    const float* __restrict__ X,
    const unsigned short* __restrict__ Wh,
    const unsigned short* __restrict__ Wl,
    float* __restrict__ Y)
{
    __shared__ alignas(16) unsigned short s_xh[128 * 32];
    __shared__ alignas(16) unsigned short s_xl[128 * 32];
    __shared__ alignas(16) unsigned short s_wh[128 * 32];
    __shared__ alignas(16) unsigned short s_wl[128 * 32];

    const int bid = blockIdx.x;
    const int nb = bid & 7;
    const int mt = bid >> 3;
    const int t = threadIdx.x;
    const int wid = t >> 6;
    const int lane = t & 63;
    const int wr = wid >> 1, wc = wid & 1;
    const int l15 = lane & 15, lg = lane >> 4;
    const int nk = (nb + 1) * 4;

    f32x4 acc[4][4] = {};

    for (int kc = 0; kc < nk; ++kc) {
        __syncthreads();
        #pragma unroll
        for (int p = 0; p < 4; ++p) {
            const int f = p * 256 + t;
            const int row = f >> 3, fc = f & 7;
            const float4 v = *reinterpret_cast<const float4*>(
                X + (size_t)(mt * 128 + row) * 1024 + kc * 32 + fc * 4);
            ushort4 hv, lv;
            hv.x = f2bf_rne(v.x); lv.x = f2bf_rne(v.x - bf2f(hv.x));
            hv.y = f2bf_rne(v.y); lv.y = f2bf_rne(v.y - bf2f(hv.y));
            hv.z = f2bf_rne(v.z); lv.z = f2bf_rne(v.z - bf2f(hv.z));
            hv.w = f2bf_rne(v.w); lv.w = f2bf_rne(v.w - bf2f(hv.w));
            const int off = lds_off(row, fc >> 1) + ((fc & 1) << 3);
            *reinterpret_cast<ushort4*>(reinterpret_cast<char*>(s_xh) + off) = hv;
            *reinterpret_cast<ushort4*>(reinterpret_cast<char*>(s_xl) + off) = lv;
        }
        #pragma unroll
        for (int p = 0; p < 2; ++p) {
            const int id = p * 256 + t;
            const int row = id >> 2, g = id & 3;
            const size_t gof = (((size_t)(nb * 32 + kc)) << 12) + (g << 10) + (row << 3);
            const int off = lds_off(row, g);
            *reinterpret_cast<short8v*>(reinterpret_cast<char*>(s_wh) + off) =
                *reinterpret_cast<const short8v*>(Wh + gof);
            *reinterpret_cast<short8v*>(reinterpret_cast<char*>(s_wl) + off) =
                *reinterpret_cast<const short8v*>(Wl + gof);
        }
        __syncthreads();

        short8v ah[4], al[4], bh[4], bl[4];
        #pragma unroll
        for (int mm = 0; mm < 4; ++mm) {
            const int off = lds_off(wr * 64 + mm * 16 + l15, lg);
            ah[mm] = *reinterpret_cast<const short8v*>(reinterpret_cast<char*>(s_xh) + off);
            al[mm] = *reinterpret_cast<const short8v*>(reinterpret_cast<char*>(s_xl) + off);
        }
        #pragma unroll
        for (int nn = 0; nn < 4; ++nn) {
            const int off = lds_off(wc * 64 + nn * 16 + l15, lg);
            bh[nn] = *reinterpret_cast<const short8v*>(reinterpret_cast<char*>(s_wh) + off);
            bl[nn] = *reinterpret_cast<const short8v*>(reinterpret_cast<char*>(s_wl) + off);
        }
        #pragma unroll
        for (int mm = 0; mm < 4; ++mm) {
            #pragma unroll
            for (int nn = 0; nn < 4; ++nn) {
                acc[mm][nn] = __builtin_amdgcn_mfma_f32_16x16x32_bf16(
                    ah[mm], bh[nn], acc[mm][nn], 0, 0, 0);
                acc[mm][nn] = __builtin_amdgcn_mfma_f32_16x16x32_bf16(
                    al[mm], bh[nn], acc[mm][nn], 0, 0, 0);
                acc[mm][nn] = __builtin_amdgcn_mfma_f32_16x16x32_bf16(
                    ah[mm], bl[nn], acc[mm][nn], 0, 0, 0);
            }
        }
    }

    #pragma unroll
    for (int mm = 0; mm < 4; ++mm) {
        const int grow = mt * 128 + wr * 64 + mm * 16 + lg * 4;
        #pragma unroll
        for (int nn = 0; nn < 4; ++nn) {
            const int gcol = nb * 128 + wc * 64 + nn * 16 + l15;
            #pragma unroll
            for (int q = 0; q < 4; ++q)
                Y[(size_t)(grow + q) * 1024 + gcol] = acc[mm][nn][q];
        }
    }
}

} // namespace

extern "C" void kernel_launch(void* const* d_in, const int* in_sizes, int n_in,
                              void* d_out, int out_size, void* d_ws, size_t ws_size,
                              hipStream_t stream) {
    const float* x   = (const float*)d_in[0];
    const float* Lre = (const float*)d_in[1];
    const float* Lim = (const float*)d_in[2];
    const float* Bre = (const float*)d_in[3];
    const float* Bim = (const float*)d_in[4];
    const float* Cre = (const float*)d_in[5];
    const float* Cim = (const float*)d_in[6];
    const float* Dm  = (const float*)d_in[7];
    float* y = (float*)d_out;

    const int positions = in_sizes[0] / 1024;          // 32768
    const int mtiles = positions / 128;                // 256

    unsigned short* Wh = (unsigned short*)d_ws;        // 2 MB
    unsigned short* Wl = Wh + 1024 * 1024;             // 2 MB
    unsigned short* Xh = Wl + 1024 * 1024;             // 64 MB
    unsigned short* Xl = Xh + (size_t)positions * 1024;

    const size_t need = (size_t)4 * 1024 * 1024
                      + (size_t)4 * positions * 1024;  // Wh+Wl + Xh+Xl bytes

    build_w_kernel<<<64 * 64, 256, 0, stream>>>(Lre, Lim, Bre, Bim, Cre, Cim, Dm, Wh, Wl);

    if (ws_size >= need) {
        split_x_kernel<<<mtiles * 32, 256, 0, stream>>>(x, Xh, Xl);
        gemm_tiled_kernel<<<mtiles * 8, 256, 0, stream>>>(Xh, Xl, Wh, Wl, y, mtiles);
    } else {
        gemm_fused_kernel<<<mtiles * 8, 256, 0, stream>>>(x, Wh, Wl, y);
    }
}

// Round 4
// 139.801 us; speedup vs baseline: 3.5813x; 1.2833x over previous
//
#include <hip/hip_runtime.h>

// ImageLRU as one GEMM: y[r,:] = W @ x[r,:], W (1024x1024, block-lower-tri)
// built on device from (Lam,B,C,D). R4:
//  - 2-term precision: y = Xh*Wh + Xh*Wl  (X rounded to bf16 once; W kept as
//    bf16 hi+lo pair => ~17 mantissa bits of W). No Xl array.
//  - GEMM K-loop: double-buffered LDS, ONE barrier per K-chunk, next-chunk
//    global_load_lds issued before current chunk's MFMA (latency overlap).
//  - Tiled operand layout in ws == exact LDS image (linear gld_lds, both-
//    sides-or-neither swizzle rule: no swizzle anywhere, conflict-free reads).

namespace {

typedef __attribute__((ext_vector_type(8))) short short8v;
typedef __attribute__((ext_vector_type(4))) float f32x4;

__device__ inline unsigned short f2bf_rne(float f) {
    unsigned u = __builtin_bit_cast(unsigned, f);
    u += 0x7fffu + ((u >> 16) & 1u);
    return (unsigned short)(u >> 16);
}
__device__ inline float bf2f(unsigned short h) {
    unsigned u = ((unsigned)h) << 16;
    return __builtin_bit_cast(float, u);
}

__device__ inline void gld_lds16(const unsigned short* g, unsigned short* l) {
    __builtin_amdgcn_global_load_lds(
        (const __attribute__((address_space(1))) unsigned int*)g,
        (__attribute__((address_space(3))) unsigned int*)l, 16, 0, 0);
}

// Tiled layout for a [128 rows][32 k] bf16 tile: elem (row,k) at
//   tile_base + ((k>>3)<<10) + (row<<3) + (k&7)   (ushort units, 4096/tile)

// ---------------- prep: build Wh/Wl in tiled layout ----------------
__global__ __launch_bounds__(256) void build_w_kernel(
    const float* __restrict__ Lre, const float* __restrict__ Lim,
    const float* __restrict__ Bre, const float* __restrict__ Bim,
    const float* __restrict__ Cre, const float* __restrict__ Cim,
    const float* __restrict__ Dm,
    unsigned short* __restrict__ Wh, unsigned short* __restrict__ Wl)
{
    const int i = blockIdx.x >> 6, j = blockIdx.x & 63;
    const int t = threadIdx.x, k = t >> 4, l = t & 15;

    const int n_g = i * 16 + k;        // W row (n dim)
    const int k_g = j * 16 + l;        // W col (k dim)
    const size_t widx = (((size_t)((n_g >> 7) * 32 + (k_g >> 5))) << 12)
                      + (((k_g >> 3) & 3) << 10) + ((n_g & 127) << 3) + (k_g & 7);

    if (j > i) { Wh[widx] = 0; Wl[widx] = 0; return; }

    __shared__ float2 Bs[16][16];
    __shared__ float2 M[16][16];
    Bs[k][l] = make_float2(Bre[t], Bim[t]);
    M[k][l]  = make_float2(k == l ? 1.f : 0.f, 0.f);
    const int delta = i - j;
    __syncthreads();

    #pragma unroll
    for (int d = 0; d < 6; ++d) {
        const int s = 1 << d;
        if (delta & s) {
            const float lr = Lre[k], li = Lim[k];
            const float2 m0 = M[k][l];
            M[k][l] = make_float2(lr * m0.x - li * m0.y, lr * m0.y + li * m0.x);
            __syncthreads();
        } else if (j + (delta & (s - 1)) >= s) {
            float2 acc = make_float2(0.f, 0.f);
            #pragma unroll
            for (int m = 0; m < 16; ++m) {
                const float2 b = Bs[k][m], v = M[m][l];
                acc.x += b.x * v.x - b.y * v.y;
                acc.y += b.x * v.y + b.y * v.x;
            }
            __syncthreads();
            M[k][l] = acc;
            __syncthreads();
        }
    }

    float w = 0.f;
    #pragma unroll
    for (int m = 0; m < 16; ++m) {
        const float2 v = M[m][l];
        w += Cre[k * 16 + m] * v.x - Cim[k * 16 + m] * v.y;
    }
    if (i == j) w += Dm[t];
    const unsigned short h = f2bf_rne(w);
    Wh[widx] = h;
    Wl[widx] = f2bf_rne(w - bf2f(h));
}

// ---------------- prep: X -> Xh bf16 (tiled layout) ----------------
__global__ __launch_bounds__(256) void split_x_kernel(
    const float* __restrict__ X, unsigned short* __restrict__ Xh)
{
    const int mt = blockIdx.x >> 5;    // 128-row tile
    const int kc = blockIdx.x & 31;    // 32-col chunk
    const int t = threadIdx.x;
    const size_t tb = ((size_t)(mt * 32 + kc)) << 12;

    #pragma unroll
    for (int p = 0; p < 4; ++p) {
        const int f = p * 256 + t;          // float4 id in [0,1024)
        const int row = f >> 3, c4 = f & 7;
        const float4 v = *reinterpret_cast<const float4*>(
            X + (size_t)(mt * 128 + row) * 1024 + kc * 32 + c4 * 4);
        ushort4 hv;
        hv.x = f2bf_rne(v.x);
        hv.y = f2bf_rne(v.y);
        hv.z = f2bf_rne(v.z);
        hv.w = f2bf_rne(v.w);
        const size_t o = tb + ((size_t)(c4 >> 1) << 10) + (row << 3) + ((c4 & 1) << 2);
        *reinterpret_cast<ushort4*>(Xh + o) = hv;
    }
}

// ---------------- main GEMM: 2-term, dbuf LDS, 1 barrier / K-chunk ----------
__global__ __launch_bounds__(256) void gemm_tiled_kernel(
    const unsigned short* __restrict__ Xh,
    const unsigned short* __restrict__ Wh, const unsigned short* __restrict__ Wl,
    float* __restrict__ Y, int mtiles)
{
    __shared__ alignas(16) unsigned short s_lds[2][3 * 4096];  // 48 KB

    const int bid = blockIdx.x;
    const int nb = 7 - bid / mtiles;   // heavy N-tiles first (LPT)
    const int mt = bid % mtiles;
    const int t = threadIdx.x;
    const int wid = t >> 6, lane = t & 63;
    const int wr = wid >> 1, wc = wid & 1;
    const int l15 = lane & 15, lg = lane >> 4;
    const int nk = (nb + 1) * 4;       // triangular K-limit (chunks of 32)

    f32x4 acc[4][4] = {};

    auto stage = [&](unsigned short* buf, int kc) {
        const size_t xb = ((size_t)(mt * 32 + kc)) << 12;
        const size_t wb = ((size_t)(nb * 32 + kc)) << 12;
        #pragma unroll
        for (int p = 0; p < 6; ++p) {
            const int e8 = (((p & 1) << 8) + t) * 8;   // ushort offset of 16B slot
            const unsigned short* src =
                (p < 2) ? (Xh + xb + e8) : (p < 4) ? (Wh + wb + e8) : (Wl + wb + e8);
            gld_lds16(src, buf + ((p >> 1) << 12) + e8);
        }
    };

    stage(s_lds[0], 0);
    __syncthreads();                    // drains vmcnt(0): buf0 ready

    int cur = 0;
    for (int kc = 0; kc < nk; ++kc) {
        if (kc + 1 < nk) stage(s_lds[cur ^ 1], kc + 1);  // overlap with MFMA below

        const unsigned short* xh = s_lds[cur];
        const unsigned short* wh = xh + 4096;
        const unsigned short* wl = xh + 8192;

        short8v ah[4], bh[4], bl[4];
        #pragma unroll
        for (int mm = 0; mm < 4; ++mm) {
            const int o = (lg << 10) + ((wr * 64 + mm * 16 + l15) << 3);
            ah[mm] = *reinterpret_cast<const short8v*>(xh + o);
        }
        #pragma unroll
        for (int nn = 0; nn < 4; ++nn) {
            const int o = (lg << 10) + ((wc * 64 + nn * 16 + l15) << 3);
            bh[nn] = *reinterpret_cast<const short8v*>(wh + o);
            bl[nn] = *reinterpret_cast<const short8v*>(wl + o);
        }
        #pragma unroll
        for (int mm = 0; mm < 4; ++mm) {
            #pragma unroll
            for (int nn = 0; nn < 4; ++nn) {
                acc[mm][nn] = __builtin_amdgcn_mfma_f32_16x16x32_bf16(
                    ah[mm], bh[nn], acc[mm][nn], 0, 0, 0);
                acc[mm][nn] = __builtin_amdgcn_mfma_f32_16x16x32_bf16(
                    ah[mm], bl[nn], acc[mm][nn], 0, 0, 0);
            }
        }
        __syncthreads();   // reads of cur done (all waves) + next buf landed
        cur ^= 1;
    }

    // ---- epilogue: C/D layout col=lane&15, row=(lane>>4)*4+q ----
    #pragma unroll
    for (int mm = 0; mm < 4; ++mm) {
        const int grow = mt * 128 + wr * 64 + mm * 16 + lg * 4;
        #pragma unroll
        for (int nn = 0; nn < 4; ++nn) {
            const int gcol = nb * 128 + wc * 64 + nn * 16 + l15;
            #pragma unroll
            for (int q = 0; q < 4; ++q)
                Y[(size_t)(grow + q) * 1024 + gcol] = acc[mm][nn][q];
        }
    }
}

} // namespace

extern "C" void kernel_launch(void* const* d_in, const int* in_sizes, int n_in,
                              void* d_out, int out_size, void* d_ws, size_t ws_size,
                              hipStream_t stream) {
    const float* x   = (const float*)d_in[0];
    const float* Lre = (const float*)d_in[1];
    const float* Lim = (const float*)d_in[2];
    const float* Bre = (const float*)d_in[3];
    const float* Bim = (const float*)d_in[4];
    const float* Cre = (const float*)d_in[5];
    const float* Cim = (const float*)d_in[6];
    const float* Dm  = (const float*)d_in[7];
    float* y = (float*)d_out;

    const int positions = in_sizes[0] / 1024;          // 32768
    const int mtiles = positions / 128;                // 256

    unsigned short* Wh = (unsigned short*)d_ws;        // 2 MB
    unsigned short* Wl = Wh + 1024 * 1024;             // 2 MB
    unsigned short* Xh = Wl + 1024 * 1024;             // 64 MB

    build_w_kernel<<<64 * 64, 256, 0, stream>>>(Lre, Lim, Bre, Bim, Cre, Cim, Dm, Wh, Wl);
    split_x_kernel<<<mtiles * 32, 256, 0, stream>>>(x, Xh);
    gemm_tiled_kernel<<<mtiles * 8, 256, 0, stream>>>(Xh, Wh, Wl, y, mtiles);
}